// Round 9
// baseline (2353.944 us; speedup 1.0000x reference)
//
#include <hip/hip_runtime.h>
#include <hip/hip_bf16.h>

#define HH 1024
#define BATCH 32
#define SSRC 256
#define SDEC 64
#define EDIM 512
#define VOC 32000
#define NBLK 256

typedef __attribute__((ext_vector_type(8))) short bf16x8_t;
typedef __attribute__((ext_vector_type(4))) float f32x4_t;

__device__ __forceinline__ float bf2f(unsigned short u) {
  union { float f; unsigned int i; } c; c.i = ((unsigned int)u) << 16; return c.f;
}
__device__ __forceinline__ unsigned short f2bf(float f) {
  union { float f; unsigned int i; } c; c.f = f;
  unsigned int r = c.i + 0x7fffu + ((c.i >> 16) & 1u);
  return (unsigned short)(r >> 16);
}
__device__ __forceinline__ f32x4_t mfma16(bf16x8_t a, bf16x8_t b, f32x4_t c) {
  return __builtin_amdgcn_mfma_f32_16x16x32_bf16(a, b, c, 0, 0, 0);
}

// ---- device-coherent (sc1) accessors: bypass non-coherent per-XCD L2, NO fences ----
__device__ __forceinline__ unsigned long long ald64(const void* p) {
  return __hip_atomic_load((const unsigned long long*)p, __ATOMIC_RELAXED,
                           __HIP_MEMORY_SCOPE_AGENT);
}
__device__ __forceinline__ void ast64(unsigned long long* p, unsigned long long v) {
  __hip_atomic_store(p, v, __ATOMIC_RELAXED, __HIP_MEMORY_SCOPE_AGENT);
}
__device__ __forceinline__ void ast32(unsigned* p, unsigned v) {
  __hip_atomic_store(p, v, __ATOMIC_RELAXED, __HIP_MEMORY_SCOPE_AGENT);
}
__device__ __forceinline__ unsigned ald32(const unsigned* p) {
  return __hip_atomic_load(p, __ATOMIC_RELAXED, __HIP_MEMORY_SCOPE_AGENT);
}
__device__ __forceinline__ void astf(float* p, float v) {
  __hip_atomic_store(p, v, __ATOMIC_RELAXED, __HIP_MEMORY_SCOPE_AGENT);
}
__device__ __forceinline__ float aldf(const float* p) {
  return __hip_atomic_load(p, __ATOMIC_RELAXED, __HIP_MEMORY_SCOPE_AGENT);
}
__device__ __forceinline__ bf16x8_t ald_bf16x8(const unsigned short* p) {
  union { unsigned long long q[2]; bf16x8_t v; } u;
  u.q[0] = ald64(p);
  u.q[1] = ald64(p + 4);
  return u.v;
}
__device__ __forceinline__ bf16x8_t ald_f32x8_bf(const float* p) {
  union { unsigned long long q; float f[2]; } a, b, c, d;
  a.q = ald64(p); b.q = ald64(p + 2); c.q = ald64(p + 4); d.q = ald64(p + 6);
  bf16x8_t r;
  r[0] = (short)f2bf(a.f[0]); r[1] = (short)f2bf(a.f[1]);
  r[2] = (short)f2bf(b.f[0]); r[3] = (short)f2bf(b.f[1]);
  r[4] = (short)f2bf(c.f[0]); r[5] = (short)f2bf(c.f[1]);
  r[6] = (short)f2bf(d.f[0]); r[7] = (short)f2bf(d.f[1]);
  return r;
}

// ---- fence-free flag barriers (sc1 flags; data already at coherence point) ----
__device__ __forceinline__ void arrive(unsigned* fl, unsigned g1, int slot) {
  asm volatile("s_waitcnt vmcnt(0)" ::: "memory");  // drain my sc1 stores/atomics
  __syncthreads();                                  // whole block done
  if (threadIdx.x == 0) ast32(&fl[slot * 16], g1);
}
__device__ __forceinline__ void pollbar128(const unsigned* fl, unsigned g1) {
  if (threadIdx.x < 64) {
    const int l = threadIdx.x;
    while (true) {
      unsigned a = ald32(&fl[l * 16]);
      unsigned b = ald32(&fl[(l + 64) * 16]);
      if (__all((a >= g1) && (b >= g1))) break;
      __builtin_amdgcn_s_sleep(1);
    }
  }
  __syncthreads();
  asm volatile("" ::: "memory");
}
__device__ __forceinline__ void pollbar64(const unsigned* fl, unsigned g1) {
  if (threadIdx.x < 64) {
    while (true) {
      unsigned a = ald32(&fl[threadIdx.x * 16]);
      if (__all(a >= g1)) break;
      __builtin_amdgcn_s_sleep(1);
    }
  }
  __syncthreads();
  asm volatile("" ::: "memory");
}

// ---------- transpose f32 (K,N) -> bf16 (N,K) ----------
__global__ void k_transpose_bf16(const float* __restrict__ in, unsigned short* __restrict__ out,
                                 int K, int N) {
  __shared__ float tile[32][33];
  int n0 = blockIdx.x * 32, k0 = blockIdx.y * 32;
  int tx = threadIdx.x, ty = threadIdx.y;
#pragma unroll
  for (int i = 0; i < 4; i++)
    tile[ty + i * 8][tx] = in[(size_t)(k0 + ty + i * 8) * N + (n0 + tx)];
  __syncthreads();
#pragma unroll
  for (int i = 0; i < 4; i++)
    out[(size_t)(n0 + ty + i * 8) * K + (k0 + tx)] = f2bf(tile[tx][ty + i * 8]);
}

// ---------- elementwise cast f32 -> bf16 ----------
__global__ void k_cast_bf16(const float* __restrict__ in, unsigned short* __restrict__ out, int n) {
  int i = (blockIdx.x * blockDim.x + threadIdx.x) * 4;
  if (i < n) {
    float4 v = *(const float4*)(in + i);
    out[i] = f2bf(v.x); out[i + 1] = f2bf(v.y); out[i + 2] = f2bf(v.z); out[i + 3] = f2bf(v.w);
  }
}

// ---------- embedding gather -> bf16 ----------
__global__ void k_embed(const int* __restrict__ seq, const float* __restrict__ emb,
                        unsigned short* __restrict__ out) {
  int t = blockIdx.x;
  int row = seq[t];
  const float* s = emb + (size_t)row * EDIM;
  unsigned short* d = out + (size_t)t * EDIM;
  for (int e = threadIdx.x; e < EDIM; e += blockDim.x) d[e] = f2bf(s[e]);
}

// ---------- big GEMM: C[M,N] = A[M,K](bf16) * B^T[N,K](bf16) + bias ----------
template <int OUT_BF16>
__global__ __launch_bounds__(256) void k_gemm_bt(const unsigned short* __restrict__ A,
                                                 const unsigned short* __restrict__ B,
                                                 const float* __restrict__ bias,
                                                 void* __restrict__ Cv, int M, int N, int K) {
  __shared__ unsigned short As[128 * 32];
  __shared__ unsigned short Bs[128 * 32];
  const int tid = threadIdx.x;
  const int wave = tid >> 6, lane = tid & 63;
  const int row0 = blockIdx.y * 128, col0 = blockIdx.x * 128;
  const int wr = (wave >> 1) * 64, wc = (wave & 1) * 64;
  const int lrow = lane & 15, lk8 = (lane >> 4) * 8;
  f32x4_t acc[4][4] = {};
  const int c1 = wave, c2 = wave + 4;
  const int sr1 = c1 * 16 + (lane >> 2), sr2 = c2 * 16 + (lane >> 2);
  const int sk = (lane & 3) * 8;
  for (int kt = 0; kt < K; kt += 32) {
    __builtin_amdgcn_global_load_lds(
        (const __attribute__((address_space(1))) unsigned int*)(A + (size_t)(row0 + sr1) * K + kt + sk),
        (__attribute__((address_space(3))) unsigned int*)(As + c1 * 512), 16, 0, 0);
    __builtin_amdgcn_global_load_lds(
        (const __attribute__((address_space(1))) unsigned int*)(A + (size_t)(row0 + sr2) * K + kt + sk),
        (__attribute__((address_space(3))) unsigned int*)(As + c2 * 512), 16, 0, 0);
    __builtin_amdgcn_global_load_lds(
        (const __attribute__((address_space(1))) unsigned int*)(B + (size_t)(col0 + sr1) * K + kt + sk),
        (__attribute__((address_space(3))) unsigned int*)(Bs + c1 * 512), 16, 0, 0);
    __builtin_amdgcn_global_load_lds(
        (const __attribute__((address_space(1))) unsigned int*)(B + (size_t)(col0 + sr2) * K + kt + sk),
        (__attribute__((address_space(3))) unsigned int*)(Bs + c2 * 512), 16, 0, 0);
    __syncthreads();
    bf16x8_t af[4], bfr[4];
#pragma unroll
    for (int i = 0; i < 4; i++) {
      af[i] = *(const bf16x8_t*)(As + (wr + i * 16 + lrow) * 32 + lk8);
      bfr[i] = *(const bf16x8_t*)(Bs + (wc + i * 16 + lrow) * 32 + lk8);
    }
#pragma unroll
    for (int i = 0; i < 4; i++)
#pragma unroll
      for (int j = 0; j < 4; j++) acc[i][j] = mfma16(af[i], bfr[j], acc[i][j]);
    __syncthreads();
  }
#pragma unroll
  for (int j = 0; j < 4; j++) {
    int col = col0 + wc + j * 16 + lrow;
    float bv = bias ? bias[col] : 0.0f;
#pragma unroll
    for (int i = 0; i < 4; i++) {
#pragma unroll
      for (int r = 0; r < 4; r++) {
        int row = row0 + wr + i * 16 + (lane >> 4) * 4 + r;
        float v = acc[i][j][r] + bv;
        if (OUT_BF16)
          ((unsigned short*)Cv)[(size_t)row * N + col] = f2bf(v);
        else
          ((float*)Cv)[(size_t)row * N + col] = v;
      }
    }
  }
}

// Weight-slice LDS staging (decoder): 32 rows (3 gates x 8 cols + pad), XOR-swizzled.
__device__ __forceinline__ void stage_wslice(unsigned short* wl, const unsigned short* WT,
                                             int j0, int tid) {
  for (int i = tid; i < 32 * 128; i += 512) {
    int lr = i >> 7, k8 = (i & 127) * 8;
    bf16x8_t v = {};
    if (lr < 24) {
      int g = lr >> 3;
      v = *(const bf16x8_t*)(WT + (size_t)(g * HH + j0 + (lr & 7)) * HH + k8);
    }
    int byt = ((lr * HH + k8) * 2) ^ ((lr & 7) << 4);
    *(bf16x8_t*)((char*)wl + byt) = v;
  }
}

// ---------- persistent encoder: 4 groups x 64 blocks (8 batches x 16 cols), 1 bar/step ----------
__global__ __launch_bounds__(512, 1) void k_enc6(
    const unsigned short* __restrict__ gx,   // [32][256][3072]
    const unsigned short* __restrict__ WhT,  // [3072][1024]
    unsigned short* __restrict__ ench,       // [32][256][1024]
    unsigned short* __restrict__ hg,         // [2][32][1024] device-coherent
    unsigned long long* __restrict__ hgt,    // [32][512] tagged (seed tag 0 for decoder)
    float* __restrict__ h0f,                 // [32][1024]
    unsigned* __restrict__ flags) {
  __shared__ __align__(16) unsigned short wl[48 * 1024];  // 96 KB: 3 gates x 16 cols
  __shared__ float gs[8][3][16][17];                      // padded: conflict-free
  __shared__ float gg[3][8][16];
  __shared__ float hpf[8][16];
  __shared__ __align__(16) unsigned short gxl[2][3][8][16];
  const int tid = threadIdx.x, bid = blockIdx.x;
  const int wave = tid >> 6, lane = tid & 63;
  const int grp = bid >> 6, slot = bid & 63;
  const int b0 = grp * 8, j0 = slot * 16;
  unsigned* fl = flags + grp * 64 * 16;
  const int kq = wave, lk = (lane >> 4) * 8, lrow = lane & 15;
  for (int i = tid; i < 48 * 128; i += 512) {
    int lr = i >> 7, k8 = (i & 127) * 8;
    bf16x8_t v = *(const bf16x8_t*)(WhT + (size_t)((lr >> 4) * HH + j0 + (lr & 15)) * HH + k8);
    int byt = ((lr * HH + k8) * 2) ^ ((lr & 7) << 4);
    *(bf16x8_t*)((char*)wl + byt) = v;
  }
  if (tid < 128) hpf[tid >> 4][tid & 15] = 0.f;
  if (tid < 48) {
    int gat = tid >> 4, bb = (tid >> 1) & 7, half = tid & 1;
    *(bf16x8_t*)&gxl[0][gat][bb][half * 8] = *(const bf16x8_t*)(
        gx + ((size_t)(b0 + bb) * SSRC) * (3 * HH) + gat * HH + j0 + half * 8);
  }
  __syncthreads();
  for (int t = 0; t < SSRC; ++t) {
    const int cur = t & 1;
    const unsigned short* hsrc = hg + (size_t)cur * (32 * HH);
    f32x4_t acc[3] = {};
#pragma unroll
    for (int ks = 0; ks < 4; ++ks) {
      int k = kq * 128 + ks * 32 + lk;
      bf16x8_t x = {};
      if (lrow < 8) x = ald_bf16x8(hsrc + (size_t)(b0 + lrow) * HH + k);
#pragma unroll
      for (int n = 0; n < 3; ++n) {
        int byt = (((n * 16 + lrow) * HH + k) * 2) ^ ((lrow & 7) << 4);
        bf16x8_t w8 = *(const bf16x8_t*)((const char*)wl + byt);
        acc[n] = mfma16(x, w8, acc[n]);
      }
    }
#pragma unroll
    for (int n = 0; n < 3; ++n)
#pragma unroll
      for (int r = 0; r < 4; ++r) gs[kq][n][(lane >> 4) * 4 + r][lrow] = acc[n][r];
    __syncthreads();
    if (tid < 384) {
      int n = tid >> 7, b = (tid >> 4) & 7, c = tid & 15;
      float s = 0.f;
#pragma unroll
      for (int q = 0; q < 8; ++q) s += gs[q][n][b][c];
      gg[n][b][c] = s;
    }
    __syncthreads();
    if (tid < 64) {
      int b = tid >> 3, jj = (tid & 7) * 2;
      int bg = b0 + b;
      float hn[2]; unsigned short hv[2];
#pragma unroll
      for (int u = 0; u < 2; ++u) {
        float xz = bf2f(gxl[cur][0][b][jj + u]);
        float xr = bf2f(gxl[cur][1][b][jj + u]);
        float xh = bf2f(gxl[cur][2][b][jj + u]);
        float z = 1.f / (1.f + expf(-(xz + gg[0][b][jj + u])));
        float r = 1.f / (1.f + expf(-(xr + gg[1][b][jj + u])));
        float cand = tanhf(xh + r * gg[2][b][jj + u]);
        hn[u] = z * hpf[b][jj + u] + (1.f - z) * cand;
        hpf[b][jj + u] = hn[u];
        hv[u] = f2bf(hn[u]);
      }
      unsigned pk = (unsigned)hv[0] | ((unsigned)hv[1] << 16);
      *(unsigned*)(ench + ((size_t)bg * SSRC + t) * HH + j0 + jj) = pk;
      ast32((unsigned*)(hg + (size_t)(cur ^ 1) * (32 * HH) + bg * HH + j0 + jj), pk);
      if (t == SSRC - 1) {
        h0f[bg * HH + j0 + jj] = hn[0];
        h0f[bg * HH + j0 + jj + 1] = hn[1];
        ast64(hgt + (size_t)bg * 512 + ((j0 + jj) >> 1), (unsigned long long)pk);  // tag 0
      }
    }
    arrive(fl, t + 1, slot);
    if (tid < 48 && t + 1 < SSRC) {  // prefetch next gx under barrier wait
      int gat = tid >> 4, bb = (tid >> 1) & 7, half = tid & 1;
      *(bf16x8_t*)&gxl[cur ^ 1][gat][bb][half * 8] = *(const bf16x8_t*)(
          gx + ((size_t)(b0 + bb) * SSRC + t + 1) * (3 * HH) + gat * HH + j0 + half * 8);
    }
    if (t < SSRC - 1) pollbar64(fl, t + 1);
  }
}

// ---------- persistent decoder: 2 groups x 128 blocks; ONE barrier/step ----------
// Region n: poll B(n-1) -> phaseB(n-1){GEMMs, gates, h_n store plain+tagged} ->
//           zero ctx3[(n+1)%3] -> phaseA(n){narrow tagged spin h_n, scores, ctx atomics} ->
//           arrive B(n). h_n sealed by B(n) (stored before arrive's vmcnt drain).
__global__ __launch_bounds__(512, 1) void k_dec8(
    const unsigned short* __restrict__ xpart,  // [32][64][3072]
    const unsigned short* __restrict__ WhDT,   // [3072][1024]
    const unsigned short* __restrict__ WxD2T,  // [3072][1024]
    const unsigned short* __restrict__ ench,   // [32][256][1024] (L2-warm slices)
    const unsigned short* __restrict__ encW,   // [32][256][1024] (L2-warm slices)
    const float* __restrict__ h0f,
    unsigned short* __restrict__ hg,           // [2][32][1024] plain h (parity n&1)
    unsigned long long* __restrict__ hgt,      // [32][512] tagged h (tag = n)
    float* __restrict__ ctx3,                  // [3][32][1024] f32 (atomics, rotation)
    float* __restrict__ denom3,                // [3][32]
    unsigned short* __restrict__ deco,         // [32][64][1024]
    unsigned* __restrict__ flags) {
  __shared__ __align__(16) unsigned short wl2[2 * 32 * 1024];  // 128 KB: [0]=WhD, [1]=WxD2
  __shared__ float gs[8][2][16][17];
  __shared__ float ggA[3][16][8], ggB[3][16][8];
  __shared__ float hpf[16][8];
  __shared__ __align__(16) unsigned short hbuf[HH];
  __shared__ float wt[32];
  __shared__ float inv[16];
  __shared__ __align__(16) unsigned short xpl[2][3][16][8];
  const int tid = threadIdx.x, bid = blockIdx.x;
  const int wave = tid >> 6, lane = tid & 63;
  const int bh = bid >> 7, slot = bid & 127;
  const int j0 = slot * 8;
  unsigned* fl = flags + bh * 128 * 16;
  const int ab = bh * 16 + (slot >> 3), s0 = (slot & 7) * 32;
  const int kq = wave, lk = (lane >> 4) * 8, lrow = lane & 15;
  stage_wslice(wl2, WhDT, j0, tid);
  stage_wslice(wl2 + 32 * 1024, WxD2T, j0, tid);
  if (tid < 128) hpf[tid >> 3][tid & 7] = h0f[(bh * 16 + (tid >> 3)) * HH + j0 + (tid & 7)];
  __syncthreads();
  for (int n = 0; n <= SDEC; ++n) {
    if (n > 0) {
      pollbar128(fl, n);  // seals ctx3[(n-1)%3], denom3[(n-1)%3], AND plain/tagged h_{n-1}
      const int cur3 = (n - 1) % 3, hpar = (n - 1) & 1;
      if (tid < 16) inv[tid] = 1.f / aldf(&denom3[cur3 * 32 + bh * 16 + tid]);
      // gh_h = h_{n-1} @ WhD
      {
        const unsigned short* hrow =
            hg + (size_t)hpar * (32 * HH) + (size_t)(bh * 16 + lrow) * HH + kq * 128 + lk;
        f32x4_t acc[2] = {};
#pragma unroll
        for (int ks = 0; ks < 4; ++ks) {
          bf16x8_t x = ald_bf16x8(hrow + ks * 32);
          int k = kq * 128 + ks * 32 + lk;
#pragma unroll
          for (int nt = 0; nt < 2; ++nt) {
            int byt = (((nt * 16 + lrow) * HH + k) * 2) ^ ((lrow & 7) << 4);
            bf16x8_t w8 = *(const bf16x8_t*)((const char*)wl2 + byt);
            acc[nt] = mfma16(x, w8, acc[nt]);
          }
        }
#pragma unroll
        for (int nt = 0; nt < 2; ++nt)
#pragma unroll
          for (int r = 0; r < 4; ++r) gs[kq][nt][(lane >> 4) * 4 + r][lrow] = acc[nt][r];
      }
      __syncthreads();
      if (tid < 384) {
        int g2 = tid >> 7, rem = tid & 127, b = rem >> 3, c = rem & 7;
        int gr = g2 * 8 + c, nt = gr >> 4, tc = gr & 15;
        float s = 0.f;
#pragma unroll
        for (int q = 0; q < 8; ++q) s += gs[q][nt][b][tc];
        ggA[g2][b][c] = s;
      }
      __syncthreads();
      // gh_c = ctx_unnorm @ WxD2
      {
        const float* cb =
            ctx3 + (size_t)cur3 * (32 * HH) + (size_t)(bh * 16 + lrow) * HH + kq * 128 + lk;
        f32x4_t acc[2] = {};
#pragma unroll
        for (int ks = 0; ks < 4; ++ks) {
          bf16x8_t x = ald_f32x8_bf(cb + ks * 32);
          int k = kq * 128 + ks * 32 + lk;
#pragma unroll
          for (int nt = 0; nt < 2; ++nt) {
            int byt = ((32 * 1024 + (nt * 16 + lrow) * HH + k) * 2) ^ ((lrow & 7) << 4);
            bf16x8_t w8 = *(const bf16x8_t*)((const char*)wl2 + byt);
            acc[nt] = mfma16(x, w8, acc[nt]);
          }
        }
#pragma unroll
        for (int nt = 0; nt < 2; ++nt)
#pragma unroll
          for (int r = 0; r < 4; ++r) gs[kq][nt][(lane >> 4) * 4 + r][lrow] = acc[nt][r];
      }
      __syncthreads();
      if (tid < 384) {
        int g2 = tid >> 7, rem = tid & 127, b = rem >> 3, c = rem & 7;
        int gr = g2 * 8 + c, nt = gr >> 4, tc = gr & 15;
        float s = 0.f;
#pragma unroll
        for (int q = 0; q < 8; ++q) s += gs[q][nt][b][tc];
        ggB[g2][b][c] = s;
      }
      __syncthreads();
      if (tid < 64) {
        int b = tid >> 2, jj = (tid & 3) * 2;
        int bg = bh * 16 + b;
        float iv = inv[b];
        unsigned short hv[2];
#pragma unroll
        for (int u = 0; u < 2; ++u) {
          float xz = bf2f(xpl[hpar][0][b][jj + u]) + ggB[0][b][jj + u] * iv;
          float xr = bf2f(xpl[hpar][1][b][jj + u]) + ggB[1][b][jj + u] * iv;
          float xh = bf2f(xpl[hpar][2][b][jj + u]) + ggB[2][b][jj + u] * iv;
          float z = 1.f / (1.f + expf(-(xz + ggA[0][b][jj + u])));
          float r = 1.f / (1.f + expf(-(xr + ggA[1][b][jj + u])));
          float cand = tanhf(xh + r * ggA[2][b][jj + u]);
          float hn = z * hpf[b][jj + u] + (1.f - z) * cand;
          hpf[b][jj + u] = hn;
          hv[u] = f2bf(hn);
        }
        unsigned pk = (unsigned)hv[0] | ((unsigned)hv[1] << 16);
        *(unsigned*)(deco + ((size_t)bg * SDEC + (n - 1)) * HH + j0 + jj) = pk;
        ast32((unsigned*)(hg + (size_t)(n & 1) * (32 * HH) + bg * HH + j0 + jj), pk);
        ast64(hgt + (size_t)bg * 512 + ((j0 + jj) >> 1),
              ((unsigned long long)(unsigned)n << 32) | pk);  // tagged h_n
      }
    }
    if (n < SDEC) {
      // zero step-(n+1) accumulators (consumed region n+2; sealed by B(n)->B(n+1))
      const int z3 = (n + 1) % 3;
      if (tid < 128)
        astf(&ctx3[(size_t)z3 * (32 * HH) + (size_t)(bh * 16) * HH + slot * 128 + tid], 0.f);
      if (slot < 16 && tid == 0) astf(&denom3[z3 * 32 + bh * 16 + slot], 0.f);
      // narrow tagged spin: attention batch's h_n row (writers: this region's phaseB)
      if (tid < 128) {
        const unsigned long long* hb = hgt + (size_t)ab * 512 + tid * 4;
        unsigned long long q0, q1, q2, q3;
        const unsigned want = (unsigned)n;
        while (true) {
          q0 = ald64(hb); q1 = ald64(hb + 1); q2 = ald64(hb + 2); q3 = ald64(hb + 3);
          bool ok = ((unsigned)(q0 >> 32) >= want) && ((unsigned)(q1 >> 32) >= want) &&
                    ((unsigned)(q2 >> 32) >= want) && ((unsigned)(q3 >> 32) >= want);
          if (__all(ok)) break;
          __builtin_amdgcn_s_sleep(1);
        }
        unsigned* hd = (unsigned*)hbuf + tid * 4;
        hd[0] = (unsigned)q0; hd[1] = (unsigned)q1;
        hd[2] = (unsigned)q2; hd[3] = (unsigned)q3;
      }
      __syncthreads();
      // scores for my 32 src rows
      {
        int r = wave * 4 + (lane >> 4);
        const unsigned short* er = encW + ((size_t)ab * SSRC + s0 + r) * HH;
        float dacc = 0.f;
#pragma unroll
        for (int it = 0; it < 8; ++it) {
          int k = it * 128 + (lane & 15) * 8;
          bf16x8_t e = *(const bf16x8_t*)(er + k);
          bf16x8_t h8 = *(const bf16x8_t*)(hbuf + k);
#pragma unroll
          for (int u = 0; u < 8; ++u)
            dacc += bf2f((unsigned short)e[u]) * bf2f((unsigned short)h8[u]);
        }
#pragma unroll
        for (int m = 1; m < 16; m <<= 1) dacc += __shfl_xor(dacc, m);
        if ((lane & 15) == 0) wt[r] = expf(dacc);  // scores O(1): no max subtraction
      }
      __syncthreads();
      if (tid < 32) {  // parallel denom partial
        float v = wt[tid];
#pragma unroll
        for (int m = 1; m < 32; m <<= 1) v += __shfl_xor(v, m);
        if (tid == 0) unsafeAtomicAdd(&denom3[(n % 3) * 32 + ab], v);
      }
      {
        int k2 = tid * 2;
        float a0 = 0.f, a1 = 0.f;
        const unsigned short* eb = ench + ((size_t)ab * SSRC + s0) * HH + k2;
#pragma unroll 4
        for (int s = 0; s < 32; ++s) {
          float w2 = wt[s];
          unsigned pk = *(const unsigned*)(eb + (size_t)s * HH);
          a0 += w2 * bf2f((unsigned short)(pk & 0xffffu));
          a1 += w2 * bf2f((unsigned short)(pk >> 16));
        }
        float* cp = ctx3 + (size_t)(n % 3) * (32 * HH) + ab * HH + k2;
        unsafeAtomicAdd(cp, a0);
        unsafeAtomicAdd(cp + 1, a1);
      }
      arrive(fl, n + 1, slot);  // drains ctx atomics + zero + h_n stores
      // prefetch xpart[n] under barrier wait (used in region n+1's gates)
      if (tid < 48) {
        int gat = tid >> 4, bb = tid & 15;
        *(bf16x8_t*)&xpl[n & 1][gat][bb][0] = *(const bf16x8_t*)(
            xpart + ((size_t)(bh * 16 + bb) * SDEC + n) * (3 * HH) + gat * HH + j0);
      }
    }
  }
}

extern "C" void kernel_launch(void* const* d_in, const int* in_sizes, int n_in,
                              void* d_out, int out_size, void* d_ws, size_t ws_size,
                              hipStream_t stream) {
  const int* src_seq = (const int*)d_in[0];
  const int* dec_seq = (const int*)d_in[1];
  const float* emb = (const float*)d_in[2];
  const float* Wx_enc = (const float*)d_in[3];
  const float* Wh_enc = (const float*)d_in[4];
  const float* b_enc = (const float*)d_in[5];
  const float* Wx_dec = (const float*)d_in[6];
  const float* Wh_dec = (const float*)d_in[7];
  const float* b_dec = (const float*)d_in[8];
  const float* W_att = (const float*)d_in[9];
  const float* W_out = (const float*)d_in[10];
  const float* b_out = (const float*)d_in[11];

  // Single-phase scratch in d_out (~128 MB < 262 MB; overwritten by final GEMM).
  char* ob = (char*)d_out;
  size_t oo = 0;
  auto oalloc = [&](size_t bytes) {
    char* p = ob + oo;
    oo += (bytes + 255) & ~(size_t)255;
    return p;
  };
  unsigned short* WxTe = (unsigned short*)oalloc((size_t)3 * HH * EDIM * 2);
  unsigned short* WhTe = (unsigned short*)oalloc((size_t)3 * HH * HH * 2);
  unsigned short* WxD1T = (unsigned short*)oalloc((size_t)3 * HH * EDIM * 2);
  unsigned short* WxD2T = (unsigned short*)oalloc((size_t)3 * HH * HH * 2);
  unsigned short* WhDT = (unsigned short*)oalloc((size_t)3 * HH * HH * 2);
  unsigned short* Wattb = (unsigned short*)oalloc((size_t)HH * HH * 2);
  unsigned short* src_e = (unsigned short*)oalloc((size_t)BATCH * SSRC * EDIM * 2);
  unsigned short* dec_e = (unsigned short*)oalloc((size_t)BATCH * SDEC * EDIM * 2);
  unsigned short* gx_enc = (unsigned short*)oalloc((size_t)BATCH * SSRC * 3 * HH * 2);
  unsigned short* xpart = (unsigned short*)oalloc((size_t)BATCH * SDEC * 3 * HH * 2);
  unsigned short* ench = (unsigned short*)oalloc((size_t)BATCH * SSRC * HH * 2);
  unsigned short* encW = (unsigned short*)oalloc((size_t)BATCH * SSRC * HH * 2);

  // Alive during final GEMM -> d_ws (~70 MB).
  char* wb = (char*)d_ws;
  size_t wo = 0;
  auto walloc = [&](size_t bytes) {
    char* p = wb + wo;
    wo += (bytes + 255) & ~(size_t)255;
    return p;
  };
  unsigned short* WoutT = (unsigned short*)walloc((size_t)VOC * HH * 2);
  unsigned short* deco = (unsigned short*)walloc((size_t)BATCH * SDEC * HH * 2);
  unsigned short* hg = (unsigned short*)walloc((size_t)2 * BATCH * HH * 2);
  unsigned long long* hgt = (unsigned long long*)walloc((size_t)BATCH * 512 * 8);
  float* h0f = (float*)walloc(BATCH * HH * 4);
  float* ctx3 = (float*)walloc((size_t)3 * BATCH * HH * 4);
  float* denom3 = (float*)walloc(3 * 32 * 4);
  unsigned* flags_e = (unsigned*)walloc(NBLK * 16 * 4);
  unsigned* flags_d = (unsigned*)walloc(NBLK * 16 * 4);
  if (wo > ws_size) return;

  dim3 tb(32, 8);
  k_transpose_bf16<<<dim3(3 * HH / 32, EDIM / 32), tb, 0, stream>>>(Wx_enc, WxTe, EDIM, 3 * HH);
  k_transpose_bf16<<<dim3(3 * HH / 32, HH / 32), tb, 0, stream>>>(Wh_enc, WhTe, HH, 3 * HH);
  k_transpose_bf16<<<dim3(3 * HH / 32, EDIM / 32), tb, 0, stream>>>(Wx_dec, WxD1T, EDIM, 3 * HH);
  k_transpose_bf16<<<dim3(3 * HH / 32, HH / 32), tb, 0, stream>>>(Wx_dec + (size_t)EDIM * 3 * HH,
                                                                  WxD2T, HH, 3 * HH);
  k_transpose_bf16<<<dim3(3 * HH / 32, HH / 32), tb, 0, stream>>>(Wh_dec, WhDT, HH, 3 * HH);
  k_transpose_bf16<<<dim3(VOC / 32, HH / 32), tb, 0, stream>>>(W_out, WoutT, HH, VOC);
  k_cast_bf16<<<(HH * HH / 4) / 256, 256, 0, stream>>>(W_att, Wattb, HH * HH);

  k_embed<<<BATCH * SSRC, 128, 0, stream>>>(src_seq, emb, src_e);
  k_embed<<<BATCH * SDEC, 128, 0, stream>>>(dec_seq, emb, dec_e);

  k_gemm_bt<1><<<dim3(3 * HH / 128, BATCH * SSRC / 128), 256, 0, stream>>>(
      src_e, WxTe, b_enc, gx_enc, BATCH * SSRC, 3 * HH, EDIM);
  k_gemm_bt<1><<<dim3(3 * HH / 128, BATCH * SDEC / 128), 256, 0, stream>>>(
      dec_e, WxD1T, b_dec, xpart, BATCH * SDEC, 3 * HH, EDIM);

  hipMemsetAsync(hg, 0, (size_t)2 * BATCH * HH * 2, stream);
  hipMemsetAsync(ctx3, 0, (size_t)3 * BATCH * HH * 4, stream);
  hipMemsetAsync(denom3, 0, 3 * 32 * 4, stream);
  hipMemsetAsync(flags_e, 0, NBLK * 16 * 4 * 2, stream);  // both flag arrays (contiguous)

  k_enc6<<<NBLK, 512, 0, stream>>>(gx_enc, WhTe, ench, hg, hgt, h0f, flags_e);

  // encW = ench @ W_att^T  (scores reassociation)
  k_gemm_bt<1><<<dim3(HH / 128, BATCH * SSRC / 128), 256, 0, stream>>>(
      ench, Wattb, nullptr, encW, BATCH * SSRC, HH, HH);

  k_dec8<<<NBLK, 512, 0, stream>>>(xpart, WhDT, WxD2T, ench, encW, h0f, hg, hgt, ctx3, denom3,
                                   deco, flags_d);

  k_gemm_bt<0><<<dim3(VOC / 128, BATCH * SDEC / 128), 256, 0, stream>>>(
      deco, WoutT, b_out, d_out, BATCH * SDEC, VOC, HH);
}

// Round 10
// 2075.686 us; speedup vs baseline: 1.1341x; 1.1341x over previous
//
#include <hip/hip_runtime.h>
#include <hip/hip_bf16.h>

#define HH 1024
#define BATCH 32
#define SSRC 256
#define SDEC 64
#define EDIM 512
#define VOC 32000
#define NBLK 256

typedef __attribute__((ext_vector_type(8))) short bf16x8_t;
typedef __attribute__((ext_vector_type(4))) float f32x4_t;

__device__ __forceinline__ float bf2f(unsigned short u) {
  union { float f; unsigned int i; } c; c.i = ((unsigned int)u) << 16; return c.f;
}
__device__ __forceinline__ unsigned short f2bf(float f) {
  union { float f; unsigned int i; } c; c.f = f;
  unsigned int r = c.i + 0x7fffu + ((c.i >> 16) & 1u);
  return (unsigned short)(r >> 16);
}
__device__ __forceinline__ f32x4_t mfma16(bf16x8_t a, bf16x8_t b, f32x4_t c) {
  return __builtin_amdgcn_mfma_f32_16x16x32_bf16(a, b, c, 0, 0, 0);
}

// ---- device-coherent (sc1) accessors: bypass non-coherent per-XCD L2, NO fences ----
__device__ __forceinline__ unsigned long long ald64(const void* p) {
  return __hip_atomic_load((const unsigned long long*)p, __ATOMIC_RELAXED,
                           __HIP_MEMORY_SCOPE_AGENT);
}
__device__ __forceinline__ void ast32(unsigned* p, unsigned v) {
  __hip_atomic_store(p, v, __ATOMIC_RELAXED, __HIP_MEMORY_SCOPE_AGENT);
}
__device__ __forceinline__ unsigned ald32(const unsigned* p) {
  return __hip_atomic_load(p, __ATOMIC_RELAXED, __HIP_MEMORY_SCOPE_AGENT);
}
__device__ __forceinline__ void astf(float* p, float v) {
  __hip_atomic_store(p, v, __ATOMIC_RELAXED, __HIP_MEMORY_SCOPE_AGENT);
}
__device__ __forceinline__ float aldf(const float* p) {
  return __hip_atomic_load(p, __ATOMIC_RELAXED, __HIP_MEMORY_SCOPE_AGENT);
}
__device__ __forceinline__ bf16x8_t ald_bf16x8(const unsigned short* p) {
  union { unsigned long long q[2]; bf16x8_t v; } u;
  u.q[0] = ald64(p);
  u.q[1] = ald64(p + 4);
  return u.v;
}
__device__ __forceinline__ bf16x8_t ald_f32x8_bf(const float* p) {
  union { unsigned long long q; float f[2]; } a, b, c, d;
  a.q = ald64(p); b.q = ald64(p + 2); c.q = ald64(p + 4); d.q = ald64(p + 6);
  bf16x8_t r;
  r[0] = (short)f2bf(a.f[0]); r[1] = (short)f2bf(a.f[1]);
  r[2] = (short)f2bf(b.f[0]); r[3] = (short)f2bf(b.f[1]);
  r[4] = (short)f2bf(c.f[0]); r[5] = (short)f2bf(c.f[1]);
  r[6] = (short)f2bf(d.f[0]); r[7] = (short)f2bf(d.f[1]);
  return r;
}

// ---- fence-free flag barriers (sc1 flags; data already at coherence point) ----
__device__ __forceinline__ void arrive(unsigned* fl, unsigned g1, int slot) {
  asm volatile("s_waitcnt vmcnt(0)" ::: "memory");  // drain my sc1 stores/atomics
  __syncthreads();                                  // whole block done
  if (threadIdx.x == 0) ast32(&fl[slot * 16], g1);
}
__device__ __forceinline__ void pollbar64(const unsigned* fl, unsigned g1) {
  if (threadIdx.x < 64) {
    while (true) {
      unsigned a = ald32(&fl[threadIdx.x * 16]);
      if (__all(a >= g1)) break;
      __builtin_amdgcn_s_sleep(1);
    }
  }
  __syncthreads();
  asm volatile("" ::: "memory");
}

// ---------- transpose f32 (K,N) -> bf16 (N,K) ----------
__global__ void k_transpose_bf16(const float* __restrict__ in, unsigned short* __restrict__ out,
                                 int K, int N) {
  __shared__ float tile[32][33];
  int n0 = blockIdx.x * 32, k0 = blockIdx.y * 32;
  int tx = threadIdx.x, ty = threadIdx.y;
#pragma unroll
  for (int i = 0; i < 4; i++)
    tile[ty + i * 8][tx] = in[(size_t)(k0 + ty + i * 8) * N + (n0 + tx)];
  __syncthreads();
#pragma unroll
  for (int i = 0; i < 4; i++)
    out[(size_t)(n0 + ty + i * 8) * K + (k0 + tx)] = f2bf(tile[tx][ty + i * 8]);
}

// ---------- elementwise cast f32 -> bf16 ----------
__global__ void k_cast_bf16(const float* __restrict__ in, unsigned short* __restrict__ out, int n) {
  int i = (blockIdx.x * blockDim.x + threadIdx.x) * 4;
  if (i < n) {
    float4 v = *(const float4*)(in + i);
    out[i] = f2bf(v.x); out[i + 1] = f2bf(v.y); out[i + 2] = f2bf(v.z); out[i + 3] = f2bf(v.w);
  }
}

// ---------- embedding gather -> bf16 ----------
__global__ void k_embed(const int* __restrict__ seq, const float* __restrict__ emb,
                        unsigned short* __restrict__ out) {
  int t = blockIdx.x;
  int row = seq[t];
  const float* s = emb + (size_t)row * EDIM;
  unsigned short* d = out + (size_t)t * EDIM;
  for (int e = threadIdx.x; e < EDIM; e += blockDim.x) d[e] = f2bf(s[e]);
}

// ---------- big GEMM: C[M,N] = A[M,K](bf16) * B^T[N,K](bf16) + bias ----------
template <int OUT_BF16>
__global__ __launch_bounds__(256) void k_gemm_bt(const unsigned short* __restrict__ A,
                                                 const unsigned short* __restrict__ B,
                                                 const float* __restrict__ bias,
                                                 void* __restrict__ Cv, int M, int N, int K) {
  __shared__ unsigned short As[128 * 32];
  __shared__ unsigned short Bs[128 * 32];
  const int tid = threadIdx.x;
  const int wave = tid >> 6, lane = tid & 63;
  const int row0 = blockIdx.y * 128, col0 = blockIdx.x * 128;
  const int wr = (wave >> 1) * 64, wc = (wave & 1) * 64;
  const int lrow = lane & 15, lk8 = (lane >> 4) * 8;
  f32x4_t acc[4][4] = {};
  const int c1 = wave, c2 = wave + 4;
  const int sr1 = c1 * 16 + (lane >> 2), sr2 = c2 * 16 + (lane >> 2);
  const int sk = (lane & 3) * 8;
  for (int kt = 0; kt < K; kt += 32) {
    __builtin_amdgcn_global_load_lds(
        (const __attribute__((address_space(1))) unsigned int*)(A + (size_t)(row0 + sr1) * K + kt + sk),
        (__attribute__((address_space(3))) unsigned int*)(As + c1 * 512), 16, 0, 0);
    __builtin_amdgcn_global_load_lds(
        (const __attribute__((address_space(1))) unsigned int*)(A + (size_t)(row0 + sr2) * K + kt + sk),
        (__attribute__((address_space(3))) unsigned int*)(As + c2 * 512), 16, 0, 0);
    __builtin_amdgcn_global_load_lds(
        (const __attribute__((address_space(1))) unsigned int*)(B + (size_t)(col0 + sr1) * K + kt + sk),
        (__attribute__((address_space(3))) unsigned int*)(Bs + c1 * 512), 16, 0, 0);
    __builtin_amdgcn_global_load_lds(
        (const __attribute__((address_space(1))) unsigned int*)(B + (size_t)(col0 + sr2) * K + kt + sk),
        (__attribute__((address_space(3))) unsigned int*)(Bs + c2 * 512), 16, 0, 0);
    __syncthreads();
    bf16x8_t af[4], bfr[4];
#pragma unroll
    for (int i = 0; i < 4; i++) {
      af[i] = *(const bf16x8_t*)(As + (wr + i * 16 + lrow) * 32 + lk8);
      bfr[i] = *(const bf16x8_t*)(Bs + (wc + i * 16 + lrow) * 32 + lk8);
    }
#pragma unroll
    for (int i = 0; i < 4; i++)
#pragma unroll
      for (int j = 0; j < 4; j++) acc[i][j] = mfma16(af[i], bfr[j], acc[i][j]);
    __syncthreads();
  }
#pragma unroll
  for (int j = 0; j < 4; j++) {
    int col = col0 + wc + j * 16 + lrow;
    float bv = bias ? bias[col] : 0.0f;
#pragma unroll
    for (int i = 0; i < 4; i++) {
#pragma unroll
      for (int r = 0; r < 4; r++) {
        int row = row0 + wr + i * 16 + (lane >> 4) * 4 + r;
        float v = acc[i][j][r] + bv;
        if (OUT_BF16)
          ((unsigned short*)Cv)[(size_t)row * N + col] = f2bf(v);
        else
          ((float*)Cv)[(size_t)row * N + col] = v;
      }
    }
  }
}

// 48-row weight slice staging (16 cols x 3 gates), XOR-swizzled.
__device__ __forceinline__ void stage_w48(unsigned short* wl, const unsigned short* WT,
                                          int j0, int tid) {
  for (int i = tid; i < 48 * 128; i += 512) {
    int lr = i >> 7, k8 = (i & 127) * 8;
    bf16x8_t v = *(const bf16x8_t*)(WT + (size_t)((lr >> 4) * HH + j0 + (lr & 15)) * HH + k8);
    int byt = ((lr * HH + k8) * 2) ^ ((lr & 7) << 4);
    *(bf16x8_t*)((char*)wl + byt) = v;
  }
}

// ---------- persistent encoder: 4 groups x 64 blocks (8 batches x 16 cols), 1 bar/step ----------
__global__ __launch_bounds__(512, 1) void k_enc6(
    const unsigned short* __restrict__ gx,   // [32][256][3072]
    const unsigned short* __restrict__ WhT,  // [3072][1024]
    unsigned short* __restrict__ ench,       // [32][256][1024]
    unsigned short* __restrict__ hg,         // [2][32][1024] device-coherent
    float* __restrict__ h0f,                 // [32][1024]
    unsigned* __restrict__ flags) {
  __shared__ __align__(16) unsigned short wl[48 * 1024];  // 96 KB: 3 gates x 16 cols
  __shared__ float gs[8][3][16][17];                      // padded: conflict-free
  __shared__ float gg[3][8][16];
  __shared__ float hpf[8][16];
  __shared__ __align__(16) unsigned short gxl[2][3][8][16];
  const int tid = threadIdx.x, bid = blockIdx.x;
  const int wave = tid >> 6, lane = tid & 63;
  const int grp = bid >> 6, slot = bid & 63;
  const int b0 = grp * 8, j0 = slot * 16;
  unsigned* fl = flags + grp * 64 * 16;
  const int kq = wave, lk = (lane >> 4) * 8, lrow = lane & 15;
  stage_w48(wl, WhT, j0, tid);
  if (tid < 128) hpf[tid >> 4][tid & 15] = 0.f;
  if (tid < 48) {
    int gat = tid >> 4, bb = (tid >> 1) & 7, half = tid & 1;
    *(bf16x8_t*)&gxl[0][gat][bb][half * 8] = *(const bf16x8_t*)(
        gx + ((size_t)(b0 + bb) * SSRC) * (3 * HH) + gat * HH + j0 + half * 8);
  }
  __syncthreads();
  for (int t = 0; t < SSRC; ++t) {
    const int cur = t & 1;
    const unsigned short* hsrc = hg + (size_t)cur * (32 * HH);
    f32x4_t acc[3] = {};
#pragma unroll
    for (int ks = 0; ks < 4; ++ks) {
      int k = kq * 128 + ks * 32 + lk;
      bf16x8_t x = {};
      if (lrow < 8) x = ald_bf16x8(hsrc + (size_t)(b0 + lrow) * HH + k);
#pragma unroll
      for (int n = 0; n < 3; ++n) {
        int byt = (((n * 16 + lrow) * HH + k) * 2) ^ ((lrow & 7) << 4);
        bf16x8_t w8 = *(const bf16x8_t*)((const char*)wl + byt);
        acc[n] = mfma16(x, w8, acc[n]);
      }
    }
#pragma unroll
    for (int n = 0; n < 3; ++n)
#pragma unroll
      for (int r = 0; r < 4; ++r) gs[kq][n][(lane >> 4) * 4 + r][lrow] = acc[n][r];
    __syncthreads();
    if (tid < 384) {
      int n = tid >> 7, b = (tid >> 4) & 7, c = tid & 15;
      float s = 0.f;
#pragma unroll
      for (int q = 0; q < 8; ++q) s += gs[q][n][b][c];
      gg[n][b][c] = s;
    }
    __syncthreads();
    if (tid < 64) {
      int b = tid >> 3, jj = (tid & 7) * 2;
      int bg = b0 + b;
      float hn[2]; unsigned short hv[2];
#pragma unroll
      for (int u = 0; u < 2; ++u) {
        float xz = bf2f(gxl[cur][0][b][jj + u]);
        float xr = bf2f(gxl[cur][1][b][jj + u]);
        float xh = bf2f(gxl[cur][2][b][jj + u]);
        float z = 1.f / (1.f + expf(-(xz + gg[0][b][jj + u])));
        float r = 1.f / (1.f + expf(-(xr + gg[1][b][jj + u])));
        float cand = tanhf(xh + r * gg[2][b][jj + u]);
        hn[u] = z * hpf[b][jj + u] + (1.f - z) * cand;
        hpf[b][jj + u] = hn[u];
        hv[u] = f2bf(hn[u]);
      }
      unsigned pk = (unsigned)hv[0] | ((unsigned)hv[1] << 16);
      *(unsigned*)(ench + ((size_t)bg * SSRC + t) * HH + j0 + jj) = pk;
      ast32((unsigned*)(hg + (size_t)(cur ^ 1) * (32 * HH) + bg * HH + j0 + jj), pk);
      if (t == SSRC - 1) {
        h0f[bg * HH + j0 + jj] = hn[0];
        h0f[bg * HH + j0 + jj + 1] = hn[1];
      }
    }
    arrive(fl, t + 1, slot);
    if (tid < 48 && t + 1 < SSRC) {  // prefetch next gx under barrier wait
      int gat = tid >> 4, bb = (tid >> 1) & 7, half = tid & 1;
      *(bf16x8_t*)&gxl[cur ^ 1][gat][bb][half * 8] = *(const bf16x8_t*)(
          gx + ((size_t)(b0 + bb) * SSRC + t + 1) * (3 * HH) + gat * HH + j0 + half * 8);
    }
    if (t < SSRC - 1) pollbar64(fl, t + 1);
  }
}

// ---------- persistent decoder: 4 groups x 64 blocks (8 batches x 16 cols), 2 bars/step ----------
// WxD2 slice in LDS (post-barrier critical path); WhD from L2-cached global (pre-barrier gh_h).
__global__ __launch_bounds__(512, 1) void k_dec9(
    const unsigned short* __restrict__ xpart,  // [32][64][3072]
    const unsigned short* __restrict__ WhDT,   // [3072][1024] (L2-resident)
    const unsigned short* __restrict__ WxD2T,  // [3072][1024]
    const unsigned short* __restrict__ ench,   // [32][256][1024] (L2/L3-warm)
    const unsigned short* __restrict__ encW,   // [32][256][1024] (L2/L3-warm)
    const float* __restrict__ h0f,
    unsigned short* __restrict__ hg,           // [2][32][1024] device-coherent
    float* __restrict__ ctxf,                  // [2][32][1024] f32 (atomics)
    float* __restrict__ denom,                 // [2][32]
    unsigned short* __restrict__ deco,         // [32][64][1024]
    unsigned* __restrict__ flags) {
  __shared__ __align__(16) unsigned short wx[48 * 1024];  // 96 KB WxD2 slice
  __shared__ float gs[8][3][16][17];
  __shared__ float ggA[3][8][16], ggB[3][8][16];
  __shared__ float hpf[8][16];
  __shared__ __align__(16) unsigned short hbuf[HH];
  __shared__ float wt[32];
  __shared__ float inv[8];
  __shared__ __align__(16) unsigned short xpl[2][3][8][16];
  const int tid = threadIdx.x, bid = blockIdx.x;
  const int wave = tid >> 6, lane = tid & 63;
  const int grp = bid >> 6, slot = bid & 63;
  const int b0 = grp * 8, j0 = slot * 16;
  unsigned* fl = flags + grp * 64 * 16;
  const int ab = b0 + (slot >> 3), s0 = (slot & 7) * 32;
  const int kq = wave, lk = (lane >> 4) * 8, lrow = lane & 15;
  stage_w48(wx, WxD2T, j0, tid);
  if (tid < 128) hpf[tid >> 4][tid & 15] = h0f[(b0 + (tid >> 4)) * HH + j0 + (tid & 15)];
  if (tid < 48) {
    int gat = tid >> 4, bb = (tid >> 1) & 7, half = tid & 1;
    *(bf16x8_t*)&xpl[0][gat][bb][half * 8] = *(const bf16x8_t*)(
        xpart + ((size_t)(b0 + bb) * SDEC) * (3 * HH) + gat * HH + j0 + half * 8);
  }
  __syncthreads();
  for (int t = 0; t < SDEC; ++t) {
    const int cur = t & 1, nxt = cur ^ 1;
    // zero next-step accumulators (group-owned; sealed by this step's B1)
    if (tid < 128)
      astf(&ctxf[(size_t)nxt * (32 * HH) + (size_t)b0 * HH + slot * 128 + tid], 0.f);
    if (slot < 8 && tid == 0) astf(&denom[nxt * 32 + b0 + slot], 0.f);
    // attention batch's h row -> LDS (sc1; sealed by B2(t-1))
    if (tid < 128) {
      unsigned long long q = ald64(hg + (size_t)cur * (32 * HH) + ab * HH + tid * 8);
      *(unsigned long long*)(hbuf + tid * 8) = q;
      q = ald64(hg + (size_t)cur * (32 * HH) + ab * HH + tid * 8 + 4);
      *(unsigned long long*)(hbuf + tid * 8 + 4) = q;
    }
    __syncthreads();
    // scores for my 32 src rows (encW: cached)
    {
      int r = wave * 4 + (lane >> 4);
      const unsigned short* er = encW + ((size_t)ab * SSRC + s0 + r) * HH;
      float dacc = 0.f;
#pragma unroll
      for (int it = 0; it < 8; ++it) {
        int k = it * 128 + (lane & 15) * 8;
        bf16x8_t e = *(const bf16x8_t*)(er + k);
        bf16x8_t h8 = *(const bf16x8_t*)(hbuf + k);
#pragma unroll
        for (int u = 0; u < 8; ++u)
          dacc += bf2f((unsigned short)e[u]) * bf2f((unsigned short)h8[u]);
      }
#pragma unroll
      for (int m = 1; m < 16; m <<= 1) dacc += __shfl_xor(dacc, m);
      if ((lane & 15) == 0) wt[r] = expf(dacc);  // scores O(1): no max subtraction
    }
    __syncthreads();
    if (tid < 32) {  // parallel denom partial
      float v = wt[tid];
#pragma unroll
      for (int m = 1; m < 32; m <<= 1) v += __shfl_xor(v, m);
      if (tid == 0) unsafeAtomicAdd(&denom[cur * 32 + ab], v);
    }
    {
      int k2 = tid * 2;
      float a0 = 0.f, a1 = 0.f;
      const unsigned short* eb = ench + ((size_t)ab * SSRC + s0) * HH + k2;
#pragma unroll 4
      for (int s = 0; s < 32; ++s) {
        float w2 = wt[s];
        unsigned pk = *(const unsigned*)(eb + (size_t)s * HH);
        a0 += w2 * bf2f((unsigned short)(pk & 0xffffu));
        a1 += w2 * bf2f((unsigned short)(pk >> 16));
      }
      float* cp = ctxf + (size_t)cur * (32 * HH) + ab * HH + k2;
      unsafeAtomicAdd(cp, a0);
      unsafeAtomicAdd(cp + 1, a1);
    }
    // gh_h = h @ WhD (h sc1; WhD from L2-cached global; pre-barrier)
    {
      const unsigned short* hsrc = hg + (size_t)cur * (32 * HH);
      f32x4_t acc[3] = {};
#pragma unroll
      for (int ks = 0; ks < 4; ++ks) {
        int k = kq * 128 + ks * 32 + lk;
        bf16x8_t x = {};
        if (lrow < 8) x = ald_bf16x8(hsrc + (size_t)(b0 + lrow) * HH + k);
#pragma unroll
        for (int n = 0; n < 3; ++n) {
          bf16x8_t w8 = *(const bf16x8_t*)(WhDT + (size_t)(n * HH + j0 + lrow) * HH + k);
          acc[n] = mfma16(x, w8, acc[n]);
        }
      }
#pragma unroll
      for (int n = 0; n < 3; ++n)
#pragma unroll
        for (int r = 0; r < 4; ++r) gs[kq][n][(lane >> 4) * 4 + r][lrow] = acc[n][r];
    }
    arrive(fl, 2 * t + 1, slot);
    pollbar64(fl, 2 * t + 1);  // seals ctx(t), denom(t)
    if (tid < 8) inv[tid] = 1.f / aldf(&denom[cur * 32 + b0 + tid]);
    if (tid < 384) {
      int n = tid >> 7, b = (tid >> 4) & 7, c = tid & 15;
      float s = 0.f;
#pragma unroll
      for (int q = 0; q < 8; ++q) s += gs[q][n][b][c];
      ggA[n][b][c] = s;
    }
    __syncthreads();
    // gh_c = ctx_unnorm @ WxD2 (LDS weights; post-barrier critical path)
    {
      const float* cb = ctxf + (size_t)cur * (32 * HH);
      f32x4_t acc[3] = {};
#pragma unroll
      for (int ks = 0; ks < 4; ++ks) {
        int k = kq * 128 + ks * 32 + lk;
        bf16x8_t x = {};
        if (lrow < 8) x = ald_f32x8_bf(cb + (size_t)(b0 + lrow) * HH + k);
#pragma unroll
        for (int n = 0; n < 3; ++n) {
          int byt = (((n * 16 + lrow) * HH + k) * 2) ^ ((lrow & 7) << 4);
          bf16x8_t w8 = *(const bf16x8_t*)((const char*)wx + byt);
          acc[n] = mfma16(x, w8, acc[n]);
        }
      }
#pragma unroll
      for (int n = 0; n < 3; ++n)
#pragma unroll
        for (int r = 0; r < 4; ++r) gs[kq][n][(lane >> 4) * 4 + r][lrow] = acc[n][r];
    }
    __syncthreads();
    if (tid < 384) {
      int n = tid >> 7, b = (tid >> 4) & 7, c = tid & 15;
      float s = 0.f;
#pragma unroll
      for (int q = 0; q < 8; ++q) s += gs[q][n][b][c];
      ggB[n][b][c] = s;
    }
    __syncthreads();
    if (tid < 64) {
      int b = tid >> 3, jj = (tid & 7) * 2;
      int bg = b0 + b;
      float iv = inv[b];
      unsigned short hv[2];
#pragma unroll
      for (int u = 0; u < 2; ++u) {
        float xz = bf2f(xpl[cur][0][b][jj + u]) + ggB[0][b][jj + u] * iv;
        float xr = bf2f(xpl[cur][1][b][jj + u]) + ggB[1][b][jj + u] * iv;
        float xh = bf2f(xpl[cur][2][b][jj + u]) + ggB[2][b][jj + u] * iv;
        float z = 1.f / (1.f + expf(-(xz + ggA[0][b][jj + u])));
        float r = 1.f / (1.f + expf(-(xr + ggA[1][b][jj + u])));
        float cand = tanhf(xh + r * ggA[2][b][jj + u]);
        float hn = z * hpf[b][jj + u] + (1.f - z) * cand;
        hpf[b][jj + u] = hn;
        hv[u] = f2bf(hn);
      }
      unsigned pk = (unsigned)hv[0] | ((unsigned)hv[1] << 16);
      *(unsigned*)(deco + ((size_t)bg * SDEC + t) * HH + j0 + jj) = pk;
      ast32((unsigned*)(hg + (size_t)nxt * (32 * HH) + bg * HH + j0 + jj), pk);
    }
    arrive(fl, 2 * t + 2, slot);
    if (tid < 48 && t + 1 < SDEC) {  // prefetch next xpart under barrier wait
      int gat = tid >> 4, bb = (tid >> 1) & 7, half = tid & 1;
      *(bf16x8_t*)&xpl[(t + 1) & 1][gat][bb][half * 8] = *(const bf16x8_t*)(
          xpart + ((size_t)(b0 + bb) * SDEC + t + 1) * (3 * HH) + gat * HH + j0 + half * 8);
    }
    if (t < SDEC - 1) pollbar64(fl, 2 * t + 2);
  }
}

extern "C" void kernel_launch(void* const* d_in, const int* in_sizes, int n_in,
                              void* d_out, int out_size, void* d_ws, size_t ws_size,
                              hipStream_t stream) {
  const int* src_seq = (const int*)d_in[0];
  const int* dec_seq = (const int*)d_in[1];
  const float* emb = (const float*)d_in[2];
  const float* Wx_enc = (const float*)d_in[3];
  const float* Wh_enc = (const float*)d_in[4];
  const float* b_enc = (const float*)d_in[5];
  const float* Wx_dec = (const float*)d_in[6];
  const float* Wh_dec = (const float*)d_in[7];
  const float* b_dec = (const float*)d_in[8];
  const float* W_att = (const float*)d_in[9];
  const float* W_out = (const float*)d_in[10];
  const float* b_out = (const float*)d_in[11];

  // Single-phase scratch in d_out (~128 MB < 262 MB; overwritten by final GEMM).
  char* ob = (char*)d_out;
  size_t oo = 0;
  auto oalloc = [&](size_t bytes) {
    char* p = ob + oo;
    oo += (bytes + 255) & ~(size_t)255;
    return p;
  };
  unsigned short* WxTe = (unsigned short*)oalloc((size_t)3 * HH * EDIM * 2);
  unsigned short* WhTe = (unsigned short*)oalloc((size_t)3 * HH * HH * 2);
  unsigned short* WxD1T = (unsigned short*)oalloc((size_t)3 * HH * EDIM * 2);
  unsigned short* WxD2T = (unsigned short*)oalloc((size_t)3 * HH * HH * 2);
  unsigned short* WhDT = (unsigned short*)oalloc((size_t)3 * HH * HH * 2);
  unsigned short* Wattb = (unsigned short*)oalloc((size_t)HH * HH * 2);
  unsigned short* src_e = (unsigned short*)oalloc((size_t)BATCH * SSRC * EDIM * 2);
  unsigned short* dec_e = (unsigned short*)oalloc((size_t)BATCH * SDEC * EDIM * 2);
  unsigned short* gx_enc = (unsigned short*)oalloc((size_t)BATCH * SSRC * 3 * HH * 2);
  unsigned short* xpart = (unsigned short*)oalloc((size_t)BATCH * SDEC * 3 * HH * 2);
  unsigned short* ench = (unsigned short*)oalloc((size_t)BATCH * SSRC * HH * 2);
  unsigned short* encW = (unsigned short*)oalloc((size_t)BATCH * SSRC * HH * 2);

  // Alive during final GEMM -> d_ws (~70 MB).
  char* wb = (char*)d_ws;
  size_t wo = 0;
  auto walloc = [&](size_t bytes) {
    char* p = wb + wo;
    wo += (bytes + 255) & ~(size_t)255;
    return p;
  };
  unsigned short* WoutT = (unsigned short*)walloc((size_t)VOC * HH * 2);
  unsigned short* deco = (unsigned short*)walloc((size_t)BATCH * SDEC * HH * 2);
  unsigned short* hg = (unsigned short*)walloc((size_t)2 * BATCH * HH * 2);
  float* h0f = (float*)walloc(BATCH * HH * 4);
  float* ctxf = (float*)walloc((size_t)2 * BATCH * HH * 4);
  float* denom = (float*)walloc(2 * 32 * 4);
  unsigned* flags_e = (unsigned*)walloc(NBLK * 16 * 4);
  unsigned* flags_d = (unsigned*)walloc(NBLK * 16 * 4);
  if (wo > ws_size) return;

  dim3 tb(32, 8);
  k_transpose_bf16<<<dim3(3 * HH / 32, EDIM / 32), tb, 0, stream>>>(Wx_enc, WxTe, EDIM, 3 * HH);
  k_transpose_bf16<<<dim3(3 * HH / 32, HH / 32), tb, 0, stream>>>(Wh_enc, WhTe, HH, 3 * HH);
  k_transpose_bf16<<<dim3(3 * HH / 32, EDIM / 32), tb, 0, stream>>>(Wx_dec, WxD1T, EDIM, 3 * HH);
  k_transpose_bf16<<<dim3(3 * HH / 32, HH / 32), tb, 0, stream>>>(Wx_dec + (size_t)EDIM * 3 * HH,
                                                                  WxD2T, HH, 3 * HH);
  k_transpose_bf16<<<dim3(3 * HH / 32, HH / 32), tb, 0, stream>>>(Wh_dec, WhDT, HH, 3 * HH);
  k_transpose_bf16<<<dim3(VOC / 32, HH / 32), tb, 0, stream>>>(W_out, WoutT, HH, VOC);
  k_cast_bf16<<<(HH * HH / 4) / 256, 256, 0, stream>>>(W_att, Wattb, HH * HH);

  k_embed<<<BATCH * SSRC, 128, 0, stream>>>(src_seq, emb, src_e);
  k_embed<<<BATCH * SDEC, 128, 0, stream>>>(dec_seq, emb, dec_e);

  k_gemm_bt<1><<<dim3(3 * HH / 128, BATCH * SSRC / 128), 256, 0, stream>>>(
      src_e, WxTe, b_enc, gx_enc, BATCH * SSRC, 3 * HH, EDIM);
  k_gemm_bt<1><<<dim3(3 * HH / 128, BATCH * SDEC / 128), 256, 0, stream>>>(
      dec_e, WxD1T, b_dec, xpart, BATCH * SDEC, 3 * HH, EDIM);

  hipMemsetAsync(hg, 0, (size_t)2 * BATCH * HH * 2, stream);
  hipMemsetAsync(ctxf, 0, (size_t)2 * BATCH * HH * 4, stream);
  hipMemsetAsync(denom, 0, 2 * 32 * 4, stream);
  hipMemsetAsync(flags_e, 0, NBLK * 16 * 4 * 2, stream);  // both flag arrays (contiguous)

  k_enc6<<<NBLK, 512, 0, stream>>>(gx_enc, WhTe, ench, hg, h0f, flags_e);

  // encW = ench @ W_att^T  (scores reassociation)
  k_gemm_bt<1><<<dim3(HH / 128, BATCH * SSRC / 128), 256, 0, stream>>>(
      ench, Wattb, nullptr, encW, BATCH * SSRC, HH, HH);

  k_dec9<<<NBLK, 512, 0, stream>>>(xpart, WhDT, WxD2T, ench, encW, h0f, hg, ctxf, denom, deco,
                                   flags_d);

  k_gemm_bt<0><<<dim3(VOC / 128, BATCH * SDEC / 128), 256, 0, stream>>>(
      deco, WoutT, b_out, d_out, BATCH * SDEC, VOC, HH);
}